// Round 1
// baseline (900.456 us; speedup 1.0000x reference)
//
#include <hip/hip_runtime.h>
#include <math.h>

#define DD 1024
#define VV 50000
#define NV1 250
#define NV2 200
#define NROWS 2048
#define SEQL 1024
#define FEPS 1e-6f

__device__ __forceinline__ float wsum64(float v) {
    v += __shfl_xor(v, 1, 64);
    v += __shfl_xor(v, 2, 64);
    v += __shfl_xor(v, 4, 64);
    v += __shfl_xor(v, 8, 64);
    v += __shfl_xor(v, 16, 64);
    v += __shfl_xor(v, 32, 64);
    return v;
}

// ---------------- HTT embedding: x[row, d1*32+d2] = sum_r core1[i1,d1,r]*core2[i2,r,d2]
__global__ __launch_bounds__(256) void k_embed(const int* __restrict__ ids,
    const float* __restrict__ core1, const float* __restrict__ core2,
    float* __restrict__ X)
{
    int row = blockIdx.x;
    int t = threadIdx.x;
    int id = ids[row];
    int i1 = id / NV2, i2 = id - i1 * NV2;
    int d = t << 2;
    int d1 = d >> 5, d2 = d & 31;
    const float* g1 = core1 + (i1 * 32 + d1) * 2;   // [d1][r]
    const float* g2 = core2 + i2 * 64 + d2;          // [r][d2]
    float a0 = g1[0], a1 = g1[1];
    float4 b0 = *(const float4*)(g2);
    float4 b1 = *(const float4*)(g2 + 32);
    float4 e;
    e.x = a0 * b0.x + a1 * b1.x;
    e.y = a0 * b0.y + a1 * b1.y;
    e.z = a0 * b0.z + a1 * b1.z;
    e.w = a0 * b0.w + a1 * b1.w;
    *(float4*)(X + row * DD + d) = e;
}

// ---------------- rmsnorm(x) @ Bm -> U[row, 0..3]
__global__ __launch_bounds__(256) void k_norm_bproj(const float* __restrict__ X,
    const float* __restrict__ nw, const float* __restrict__ Bm,
    float* __restrict__ U)
{
    __shared__ float sred[4];
    __shared__ float spart[4][4];
    __shared__ float srms;
    int row = blockIdx.x, t = threadIdx.x;
    int lane = t & 63, wave = t >> 6;
    float4 x4 = *(const float4*)(X + row * DD + (t << 2));
    float ssq = x4.x * x4.x + x4.y * x4.y + x4.z * x4.z + x4.w * x4.w;
    ssq = wsum64(ssq);
    if (lane == 0) sred[wave] = ssq;
    __syncthreads();
    if (t == 0) srms = rsqrtf((sred[0] + sred[1] + sred[2] + sred[3]) * (1.0f / DD) + FEPS);
    __syncthreads();
    float rms = srms;
    float4 w4 = *(const float4*)(nw + (t << 2));
    float xn[4];
    xn[0] = x4.x * rms * w4.x; xn[1] = x4.y * rms * w4.y;
    xn[2] = x4.z * rms * w4.z; xn[3] = x4.w * rms * w4.w;
    float p0 = 0.f, p1 = 0.f, p2 = 0.f, p3 = 0.f;
    #pragma unroll
    for (int c = 0; c < 4; c++) {
        float4 bm = *(const float4*)(Bm + ((t << 2) + c) * 4);
        p0 += xn[c] * bm.x; p1 += xn[c] * bm.y; p2 += xn[c] * bm.z; p3 += xn[c] * bm.w;
    }
    p0 = wsum64(p0); p1 = wsum64(p1); p2 = wsum64(p2); p3 = wsum64(p3);
    if (lane == 0) {
        spart[wave][0] = p0; spart[wave][1] = p1; spart[wave][2] = p2; spart[wave][3] = p3;
    }
    __syncthreads();
    if (t < 4)
        U[row * 4 + t] = spart[0][t] + spart[1][t] + spart[2][t] + spart[3][t];
}

// ---------------- rank-4 semiseparable scan: 8 chains (b,r), 1 wave each
__global__ __launch_bounds__(64) void k_scan(const float* __restrict__ U,
    const float* __restrict__ adec, float* __restrict__ HS)
{
    int chain = blockIdx.x;          // 0..7
    int b = chain >> 2, r = chain & 3;
    int lane = threadIdx.x;
    float a = adec[r];
    const float* u = U + b * SEQL * 4 + r;
    float* hs = HS + b * SEQL * 4 + r;
    int s0 = lane << 4;              // 16 elements per lane
    float uloc[16];
    #pragma unroll
    for (int i = 0; i < 16; i++) uloc[i] = u[(s0 + i) * 4];
    float h = 0.f;
    #pragma unroll
    for (int i = 0; i < 16; i++) h = a * h + uloc[i];
    // a^16
    float a2 = a * a, a4 = a2 * a2, a8 = a4 * a4, a16 = a8 * a8;
    // inclusive segmented scan over lane-segments: T(h) = A*h + B
    float A = a16, B = h;
    #pragma unroll
    for (int off = 1; off < 64; off <<= 1) {
        float Bp = __shfl_up(B, off, 64);
        float Ap = __shfl_up(A, off, 64);
        if (lane >= off) { B = B + A * Bp; A = A * Ap; }
    }
    float carry = __shfl_up(B, 1, 64);
    if (lane == 0) carry = 0.f;
    h = carry;
    #pragma unroll
    for (int i = 0; i < 16; i++) {
        h = a * h + uloc[i];
        hs[(s0 + i) * 4] = h;
    }
}

// ---------------- x += HS@Cm ; xn = rmsnorm(x); x += gelu(xn@W1)@W2
__global__ __launch_bounds__(256) void k_ssm_ffn(float* __restrict__ X,
    const float* __restrict__ HS, const float* __restrict__ Cm,
    const float* __restrict__ nw, const float* __restrict__ W1,
    const float* __restrict__ W2)
{
    __shared__ float sred[4];
    __shared__ float spart[4][8];
    __shared__ float sg[8];
    __shared__ float srms;
    int row = blockIdx.x, t = threadIdx.x;
    int lane = t & 63, wave = t >> 6;
    int d = t << 2;
    float4 x4 = *(const float4*)(X + row * DD + d);
    float4 hv = *(const float4*)(HS + row * 4);
    float4 c0 = *(const float4*)(Cm + 0 * DD + d);
    float4 c1 = *(const float4*)(Cm + 1 * DD + d);
    float4 c2 = *(const float4*)(Cm + 2 * DD + d);
    float4 c3 = *(const float4*)(Cm + 3 * DD + d);
    x4.x += hv.x * c0.x + hv.y * c1.x + hv.z * c2.x + hv.w * c3.x;
    x4.y += hv.x * c0.y + hv.y * c1.y + hv.z * c2.y + hv.w * c3.y;
    x4.z += hv.x * c0.z + hv.y * c1.z + hv.z * c2.z + hv.w * c3.z;
    x4.w += hv.x * c0.w + hv.y * c1.w + hv.z * c2.w + hv.w * c3.w;
    float ssq = x4.x * x4.x + x4.y * x4.y + x4.z * x4.z + x4.w * x4.w;
    ssq = wsum64(ssq);
    if (lane == 0) sred[wave] = ssq;
    __syncthreads();
    if (t == 0) srms = rsqrtf((sred[0] + sred[1] + sred[2] + sred[3]) * (1.0f / DD) + FEPS);
    __syncthreads();
    float rms = srms;
    float4 w4 = *(const float4*)(nw + d);
    float xn[4];
    xn[0] = x4.x * rms * w4.x; xn[1] = x4.y * rms * w4.y;
    xn[2] = x4.z * rms * w4.z; xn[3] = x4.w * rms * w4.w;
    float p[8];
    #pragma unroll
    for (int j = 0; j < 8; j++) p[j] = 0.f;
    #pragma unroll
    for (int c = 0; c < 4; c++) {
        const float* w1r = W1 + (d + c) * 8;
        float4 a0 = *(const float4*)(w1r);
        float4 a1 = *(const float4*)(w1r + 4);
        p[0] += xn[c] * a0.x; p[1] += xn[c] * a0.y; p[2] += xn[c] * a0.z; p[3] += xn[c] * a0.w;
        p[4] += xn[c] * a1.x; p[5] += xn[c] * a1.y; p[6] += xn[c] * a1.z; p[7] += xn[c] * a1.w;
    }
    #pragma unroll
    for (int j = 0; j < 8; j++) p[j] = wsum64(p[j]);
    if (lane == 0) {
        #pragma unroll
        for (int j = 0; j < 8; j++) spart[wave][j] = p[j];
    }
    __syncthreads();
    if (t < 8) {
        float v = spart[0][t] + spart[1][t] + spart[2][t] + spart[3][t];
        const float kC = 0.7978845608028654f;   // sqrt(2/pi)
        float v3 = v * v * v;
        sg[t] = 0.5f * v * (1.0f + tanhf(kC * (v + 0.044715f * v3)));
    }
    __syncthreads();
    float4 dl; dl.x = 0.f; dl.y = 0.f; dl.z = 0.f; dl.w = 0.f;
    #pragma unroll
    for (int j = 0; j < 8; j++) {
        float g = sg[j];
        float4 w2 = *(const float4*)(W2 + j * DD + d);
        dl.x += g * w2.x; dl.y += g * w2.y; dl.z += g * w2.z; dl.w += g * w2.w;
    }
    x4.x += dl.x; x4.y += dl.y; x4.z += dl.z; x4.w += dl.w;
    *(float4*)(X + row * DD + d) = x4;
}

// ---------------- final rmsnorm + factorized logits
// logits[row, i1*200+i2] = sum_k c2m[i2][k] * W[i1][k],  k=r*32+d2
// W[i1][r*32+d2] = sum_d1 core1[i1,d1,r] * xn[d1*32+d2]   (built in LDS, half i1-range at a time)
__global__ __launch_bounds__(256) void k_logits(const float* __restrict__ X,
    const float* __restrict__ fw, const float* __restrict__ core1,
    const float* __restrict__ core2, float* __restrict__ out)
{
    __shared__ float xs[DD];
    __shared__ float wl[125 * 64];
    __shared__ float sred[4];
    __shared__ float srms;
    int row = blockIdx.x, t = threadIdx.x;
    int lane = t & 63, wave = t >> 6;
    // final rmsnorm into LDS
    float4 x4 = *(const float4*)(X + row * DD + (t << 2));
    float ssq = x4.x * x4.x + x4.y * x4.y + x4.z * x4.z + x4.w * x4.w;
    ssq = wsum64(ssq);
    if (lane == 0) sred[wave] = ssq;
    __syncthreads();
    if (t == 0) srms = rsqrtf((sred[0] + sred[1] + sred[2] + sred[3]) * (1.0f / DD) + FEPS);
    __syncthreads();
    float rms = srms;
    float4 w4 = *(const float4*)(fw + (t << 2));
    float4 xn;
    xn.x = x4.x * rms * w4.x; xn.y = x4.y * rms * w4.y;
    xn.z = x4.z * rms * w4.z; xn.w = x4.w * rms * w4.w;
    *(float4*)(xs + (t << 2)) = xn;
    // per-lane core2 row (i2 = t) in registers
    bool act = (t < NV2);
    int i2 = act ? t : 0;
    float c2r[64];
    {
        const float4* c2p = (const float4*)(core2 + i2 * 64);
        #pragma unroll
        for (int k = 0; k < 16; k++) {
            float4 v = c2p[k];
            c2r[4 * k + 0] = v.x; c2r[4 * k + 1] = v.y;
            c2r[4 * k + 2] = v.z; c2r[4 * k + 3] = v.w;
        }
    }
    float* op = out + (size_t)row * VV + t;
    #pragma unroll 1
    for (int half = 0; half < 2; half++) {
        int i1base = half * 125;
        __syncthreads();   // xs ready / previous-half reads done
        // build W tile (125 i1 x 64 k) into LDS: 2000 float4s over 256 threads
        for (int q = t; q < 125 * 16; q += 256) {
            int i1l = q >> 4;
            int kq = q & 15;
            int r = kq >> 3, d2b = (kq & 7) << 2;
            const float* c1 = core1 + (i1base + i1l) * 64 + r;   // [d1][r], stride 2
            float a0 = 0.f, a1 = 0.f, a2 = 0.f, a3 = 0.f;
            #pragma unroll
            for (int d1 = 0; d1 < 32; d1++) {
                float cv = c1[d1 * 2];
                float4 xv = *(const float4*)(xs + d1 * 32 + d2b);
                a0 += cv * xv.x; a1 += cv * xv.y; a2 += cv * xv.z; a3 += cv * xv.w;
            }
            float4 w; w.x = a0; w.y = a1; w.z = a2; w.w = a3;
            *(float4*)(wl + i1l * 64 + (kq << 2)) = w;
        }
        __syncthreads();
        // dot-64 per output; W reads are uniform (broadcast), c2 in regs
        for (int i1l = 0; i1l < 125; i1l++) {
            const float4* wp = (const float4*)(wl + i1l * 64);
            float acc = 0.f;
            #pragma unroll
            for (int k = 0; k < 16; k++) {
                float4 w = wp[k];
                acc += w.x * c2r[4 * k + 0] + w.y * c2r[4 * k + 1]
                     + w.z * c2r[4 * k + 2] + w.w * c2r[4 * k + 3];
            }
            if (act) op[(i1base + i1l) * NV2] = acc;
        }
    }
}

extern "C" void kernel_launch(void* const* d_in, const int* in_sizes, int n_in,
                              void* d_out, int out_size, void* d_ws, size_t ws_size,
                              hipStream_t stream)
{
    const int*   ids    = (const int*)d_in[0];
    const float* core1  = (const float*)d_in[1];   // [250,32,2]
    const float* core2  = (const float*)d_in[2];   // [200,2,32]
    const float* norm_w = (const float*)d_in[3];   // [4,1024]
    const float* adec   = (const float*)d_in[4];   // [4,4]
    const float* Bm     = (const float*)d_in[5];   // [4,1024,4]
    const float* Cm     = (const float*)d_in[6];   // [4,4,1024]
    const float* W1     = (const float*)d_in[7];   // [4,1024,8]
    const float* W2     = (const float*)d_in[8];   // [4,8,1024]
    const float* fw     = (const float*)d_in[9];   // [1024]
    float* out = (float*)d_out;

    float* X  = (float*)d_ws;                       // [2048,1024]
    float* U  = X + NROWS * DD;                     // [2048,4]
    float* HS = U + NROWS * 4;                      // [2048,4]

    k_embed<<<NROWS, 256, 0, stream>>>(ids, core1, core2, X);
    for (int l = 0; l < 4; l++) {
        k_norm_bproj<<<NROWS, 256, 0, stream>>>(X, norm_w + l * DD, Bm + l * DD * 4, U);
        k_scan<<<8, 64, 0, stream>>>(U, adec + l * 4, HS);
        k_ssm_ffn<<<NROWS, 256, 0, stream>>>(X, HS, Cm + l * 4 * DD,
                                             norm_w + l * DD, W1 + l * DD * 8, W2 + l * 8 * DD);
    }
    k_logits<<<NROWS, 256, 0, stream>>>(X, fw, core1, core2, out);
}

// Round 4
// 593.107 us; speedup vs baseline: 1.5182x; 1.5182x over previous
//
#include <hip/hip_runtime.h>
#include <math.h>

#define DD 1024
#define VV 50000
#define NV2 200
#define NROWS 2048
#define SEQL 1024
#define FEPS 1e-6f

typedef __attribute__((ext_vector_type(8))) short short8;
typedef __attribute__((ext_vector_type(4))) float f32x4;

__device__ __forceinline__ float wsum64(float v) {
    v += __shfl_xor(v, 1, 64);
    v += __shfl_xor(v, 2, 64);
    v += __shfl_xor(v, 4, 64);
    v += __shfl_xor(v, 8, 64);
    v += __shfl_xor(v, 16, 64);
    v += __shfl_xor(v, 32, 64);
    return v;
}

__device__ __forceinline__ unsigned short f2bf_rn(float f) {
    unsigned u = __builtin_bit_cast(unsigned, f);
    unsigned r = u + 0x7FFFu + ((u >> 16) & 1u);
    return (unsigned short)(r >> 16);
}
__device__ __forceinline__ float bf2f(unsigned short h) {
    unsigned u = ((unsigned)h) << 16;
    return __builtin_bit_cast(float, u);
}

// ---------------- embed + layer-0 rmsnorm + B-projection
__global__ __launch_bounds__(256) void k_embed_bproj(const int* __restrict__ ids,
    const float* __restrict__ core1, const float* __restrict__ core2,
    const float* __restrict__ nw, const float* __restrict__ Bm,
    float* __restrict__ X, float* __restrict__ U)
{
    __shared__ float sred[4];
    __shared__ float spart[4][4];
    __shared__ float srms;
    int row = blockIdx.x, t = threadIdx.x;
    int lane = t & 63, wave = t >> 6;
    int id = ids[row];
    int i1 = id / NV2, i2 = id - i1 * NV2;
    int d = t << 2;
    int d1 = d >> 5, d2 = d & 31;
    const float* g1 = core1 + (i1 * 32 + d1) * 2;
    const float* g2 = core2 + i2 * 64 + d2;
    float a0 = g1[0], a1 = g1[1];
    float4 b0 = *(const float4*)(g2);
    float4 b1 = *(const float4*)(g2 + 32);
    float4 x4;
    x4.x = a0 * b0.x + a1 * b1.x;
    x4.y = a0 * b0.y + a1 * b1.y;
    x4.z = a0 * b0.z + a1 * b1.z;
    x4.w = a0 * b0.w + a1 * b1.w;
    *(float4*)(X + row * DD + d) = x4;
    // rmsnorm + Bm projection
    float ssq = x4.x * x4.x + x4.y * x4.y + x4.z * x4.z + x4.w * x4.w;
    ssq = wsum64(ssq);
    if (lane == 0) sred[wave] = ssq;
    __syncthreads();
    if (t == 0) srms = rsqrtf((sred[0] + sred[1] + sred[2] + sred[3]) * (1.0f / DD) + FEPS);
    __syncthreads();
    float rms = srms;
    float4 w4 = *(const float4*)(nw + d);
    float xn[4];
    xn[0] = x4.x * rms * w4.x; xn[1] = x4.y * rms * w4.y;
    xn[2] = x4.z * rms * w4.z; xn[3] = x4.w * rms * w4.w;
    float p0 = 0.f, p1 = 0.f, p2 = 0.f, p3 = 0.f;
    #pragma unroll
    for (int c = 0; c < 4; c++) {
        float4 bm = *(const float4*)(Bm + (d + c) * 4);
        p0 += xn[c] * bm.x; p1 += xn[c] * bm.y; p2 += xn[c] * bm.z; p3 += xn[c] * bm.w;
    }
    p0 = wsum64(p0); p1 = wsum64(p1); p2 = wsum64(p2); p3 = wsum64(p3);
    if (lane == 0) {
        spart[wave][0] = p0; spart[wave][1] = p1; spart[wave][2] = p2; spart[wave][3] = p3;
    }
    __syncthreads();
    if (t < 4)
        U[row * 4 + t] = spart[0][t] + spart[1][t] + spart[2][t] + spart[3][t];
}

// ---------------- fused layer: closed-form scan + Cm + rmsnorm + FFN + residual
//                  (+ next layer's rmsnorm + B-projection)
__global__ __launch_bounds__(256) void k_layer(
    float* __restrict__ X, const float* __restrict__ Uin,
    const float* __restrict__ adec, const float* __restrict__ Cm,
    const float* __restrict__ nw, const float* __restrict__ W1,
    const float* __restrict__ W2, const float* __restrict__ nw_next,
    const float* __restrict__ Bm_next, float* __restrict__ Uout, int has_next)
{
    __shared__ float sred[4];
    __shared__ float spart[4][8];
    __shared__ float shv[4];
    __shared__ float sg[8];
    __shared__ float srms;
    int row = blockIdx.x, t = threadIdx.x;
    int b = row >> 10, s = row & 1023;
    int lane = t & 63, wave = t >> 6;
    int d = t << 2;
    // ---- closed-form rank-4 scan: hv[r] = sum_{s'<=s} a_r^{s-s'} u[b,s',r]
    // Thread t covers s' in {t, t+256, ...} <= s, iterated DOWNWARD from the
    // largest one so the weight update is *= a^256 (decay for older tokens).
    float4 av = *(const float4*)(adec);
    float hx = 0.f, hy = 0.f, hz = 0.f, hw = 0.f;
    if (t <= s) {
        int nterm = ((s - t) >> 8) + 1;
        int sp = t + ((s - t) & ~255);          // largest s' == t (mod 256), <= s
        float e = (float)(s - sp);              // in [0,255]
        float wx = powf(av.x, e), wy = powf(av.y, e), wz = powf(av.z, e), ww = powf(av.w, e);
        float cx = powf(av.x, 256.f), cy = powf(av.y, 256.f), cz = powf(av.z, 256.f), cw = powf(av.w, 256.f);
        for (int it = 0; it < nterm; it++, sp -= 256) {
            float4 u4 = *(const float4*)(Uin + ((b << 10) + sp) * 4);
            hx += wx * u4.x; hy += wy * u4.y; hz += wz * u4.z; hw += ww * u4.w;
            wx *= cx; wy *= cy; wz *= cz; ww *= cw;
        }
    }
    hx = wsum64(hx); hy = wsum64(hy); hz = wsum64(hz); hw = wsum64(hw);
    if (lane == 0) {
        spart[wave][0] = hx; spart[wave][1] = hy; spart[wave][2] = hz; spart[wave][3] = hw;
    }
    __syncthreads();
    if (t < 4) shv[t] = spart[0][t] + spart[1][t] + spart[2][t] + spart[3][t];
    __syncthreads();
    float4 hv; hv.x = shv[0]; hv.y = shv[1]; hv.z = shv[2]; hv.w = shv[3];
    // ---- x += hv @ Cm
    float4 x4 = *(const float4*)(X + row * DD + d);
    float4 c0 = *(const float4*)(Cm + 0 * DD + d);
    float4 c1 = *(const float4*)(Cm + 1 * DD + d);
    float4 c2 = *(const float4*)(Cm + 2 * DD + d);
    float4 c3 = *(const float4*)(Cm + 3 * DD + d);
    x4.x += hv.x * c0.x + hv.y * c1.x + hv.z * c2.x + hv.w * c3.x;
    x4.y += hv.x * c0.y + hv.y * c1.y + hv.z * c2.y + hv.w * c3.y;
    x4.z += hv.x * c0.z + hv.y * c1.z + hv.z * c2.z + hv.w * c3.z;
    x4.w += hv.x * c0.w + hv.y * c1.w + hv.z * c2.w + hv.w * c3.w;
    // ---- rmsnorm + FFN
    float ssq = x4.x * x4.x + x4.y * x4.y + x4.z * x4.z + x4.w * x4.w;
    ssq = wsum64(ssq);
    if (lane == 0) sred[wave] = ssq;
    __syncthreads();
    if (t == 0) srms = rsqrtf((sred[0] + sred[1] + sred[2] + sred[3]) * (1.0f / DD) + FEPS);
    __syncthreads();
    float rms = srms;
    float4 w4 = *(const float4*)(nw + d);
    float xn[4];
    xn[0] = x4.x * rms * w4.x; xn[1] = x4.y * rms * w4.y;
    xn[2] = x4.z * rms * w4.z; xn[3] = x4.w * rms * w4.w;
    float p[8];
    #pragma unroll
    for (int j = 0; j < 8; j++) p[j] = 0.f;
    #pragma unroll
    for (int c = 0; c < 4; c++) {
        const float* w1r = W1 + (d + c) * 8;
        float4 q0 = *(const float4*)(w1r);
        float4 q1 = *(const float4*)(w1r + 4);
        p[0] += xn[c] * q0.x; p[1] += xn[c] * q0.y; p[2] += xn[c] * q0.z; p[3] += xn[c] * q0.w;
        p[4] += xn[c] * q1.x; p[5] += xn[c] * q1.y; p[6] += xn[c] * q1.z; p[7] += xn[c] * q1.w;
    }
    #pragma unroll
    for (int j = 0; j < 8; j++) p[j] = wsum64(p[j]);
    if (lane == 0) {
        #pragma unroll
        for (int j = 0; j < 8; j++) spart[wave][j] = p[j];
    }
    __syncthreads();
    if (t < 8) {
        float v = spart[0][t] + spart[1][t] + spart[2][t] + spart[3][t];
        const float kC = 0.7978845608028654f;
        float v3 = v * v * v;
        sg[t] = 0.5f * v * (1.0f + tanhf(kC * (v + 0.044715f * v3)));
    }
    __syncthreads();
    float4 dl; dl.x = 0.f; dl.y = 0.f; dl.z = 0.f; dl.w = 0.f;
    #pragma unroll
    for (int j = 0; j < 8; j++) {
        float g = sg[j];
        float4 w2 = *(const float4*)(W2 + j * DD + d);
        dl.x += g * w2.x; dl.y += g * w2.y; dl.z += g * w2.z; dl.w += g * w2.w;
    }
    x4.x += dl.x; x4.y += dl.y; x4.z += dl.z; x4.w += dl.w;
    *(float4*)(X + row * DD + d) = x4;
    // ---- next layer's rmsnorm + B-projection
    if (has_next) {
        float s2 = x4.x * x4.x + x4.y * x4.y + x4.z * x4.z + x4.w * x4.w;
        s2 = wsum64(s2);
        if (lane == 0) sred[wave] = s2;
        __syncthreads();
        if (t == 0) srms = rsqrtf((sred[0] + sred[1] + sred[2] + sred[3]) * (1.0f / DD) + FEPS);
        __syncthreads();
        float rms2 = srms;
        float4 nw2 = *(const float4*)(nw_next + d);
        float y[4];
        y[0] = x4.x * rms2 * nw2.x; y[1] = x4.y * rms2 * nw2.y;
        y[2] = x4.z * rms2 * nw2.z; y[3] = x4.w * rms2 * nw2.w;
        float q0 = 0.f, q1 = 0.f, q2 = 0.f, q3 = 0.f;
        #pragma unroll
        for (int c = 0; c < 4; c++) {
            float4 bm = *(const float4*)(Bm_next + (d + c) * 4);
            q0 += y[c] * bm.x; q1 += y[c] * bm.y; q2 += y[c] * bm.z; q3 += y[c] * bm.w;
        }
        q0 = wsum64(q0); q1 = wsum64(q1); q2 = wsum64(q2); q3 = wsum64(q3);
        if (lane == 0) {
            spart[wave][0] = q0; spart[wave][1] = q1; spart[wave][2] = q2; spart[wave][3] = q3;
        }
        __syncthreads();
        if (t < 4)
            Uout[row * 4 + t] = spart[0][t] + spart[1][t] + spart[2][t] + spart[3][t];
    }
}

// ---------------- final rmsnorm + factorized logits via bf16 hi/lo MFMA
// W[i1][k] = sum_d1 core1[i1,d1,r]*xs[d1*32+d2], k=r*32+d2  (fp32, split to bf16 hi/lo in LDS)
// logits[i1,i2] = sum_k W[i1][k]*core2[i2][k]  via mfma_f32_16x16x32_bf16,
//   3 terms: Whi*Bhi + Wlo*Bhi + Whi*Blo   (~fp32 accuracy)
__global__ __launch_bounds__(256) void k_logits(const float* __restrict__ X,
    const float* __restrict__ fw, const float* __restrict__ core1,
    const float* __restrict__ core2, float* __restrict__ out)
{
    __shared__ __align__(16) float xs[DD];
    __shared__ __align__(16) unsigned short whi[256 * 64];
    __shared__ __align__(16) unsigned short wlo[256 * 64];
    __shared__ float sred[4];
    __shared__ float srms;
    int t = threadIdx.x;
    int lane = t & 63, wave = t >> 6;
    size_t obase = (size_t)blockIdx.x * VV;
    // phase 1: final rmsnorm -> xs
    float4 x4 = *(const float4*)(X + blockIdx.x * DD + (t << 2));
    float ssq = x4.x * x4.x + x4.y * x4.y + x4.z * x4.z + x4.w * x4.w;
    ssq = wsum64(ssq);
    if (lane == 0) sred[wave] = ssq;
    __syncthreads();
    if (t == 0) srms = rsqrtf((sred[0] + sred[1] + sred[2] + sred[3]) * (1.0f / DD) + FEPS);
    __syncthreads();
    float rms = srms;
    float4 w4 = *(const float4*)(fw + (t << 2));
    float4 xn;
    xn.x = x4.x * rms * w4.x; xn.y = x4.y * rms * w4.y;
    xn.z = x4.z * rms * w4.z; xn.w = x4.w * rms * w4.w;
    *(float4*)(xs + (t << 2)) = xn;
    __syncthreads();
    // phase 2: W build (thread t = row i1), acc[idx] covers k = idx*4..idx*4+3
    {
        int i1c = min(t, 249);
        float4 acc[16];
        #pragma unroll
        for (int j = 0; j < 16; j++) { acc[j].x = 0.f; acc[j].y = 0.f; acc[j].z = 0.f; acc[j].w = 0.f; }
        #pragma unroll
        for (int d1 = 0; d1 < 32; d1++) {
            float2 c = *(const float2*)(core1 + i1c * 64 + d1 * 2);
            #pragma unroll
            for (int q = 0; q < 8; q++) {
                float4 xv = *(const float4*)(xs + d1 * 32 + (q << 2));
                acc[q].x += c.x * xv.x; acc[q].y += c.x * xv.y;
                acc[q].z += c.x * xv.z; acc[q].w += c.x * xv.w;
                acc[8 + q].x += c.y * xv.x; acc[8 + q].y += c.y * xv.y;
                acc[8 + q].z += c.y * xv.z; acc[8 + q].w += c.y * xv.w;
            }
        }
        int swz = t & 7;
        #pragma unroll
        for (int sl = 0; sl < 8; sl++) {
            float v[8] = { acc[2 * sl].x, acc[2 * sl].y, acc[2 * sl].z, acc[2 * sl].w,
                           acc[2 * sl + 1].x, acc[2 * sl + 1].y, acc[2 * sl + 1].z, acc[2 * sl + 1].w };
            short8 ph, pl;
            #pragma unroll
            for (int e = 0; e < 8; e++) {
                unsigned short hb = f2bf_rn(v[e]);
                ph[e] = (short)hb;
                pl[e] = (short)f2bf_rn(v[e] - bf2f(hb));
            }
            int off = t * 64 + ((sl ^ swz) << 3);
            *(short8*)(whi + off) = ph;
            *(short8*)(wlo + off) = pl;
        }
    }
    __syncthreads();
    // phase 3: MFMA  (wave handles n-tiles wave, wave+4, wave+8, wave+12)
    int g16 = lane >> 4;      // k-group 0..3
    int cl = lane & 15;       // N (i2) / M (i1) in-tile index
    short8 bh[4][2], bl[4][2];
    #pragma unroll
    for (int i = 0; i < 4; i++) {
        int n = wave + (i << 2);
        int ne = min(n, 12);
        int jc = min(ne * 16 + cl, NV2 - 1);
        #pragma unroll
        for (int g = 0; g < 2; g++) {
            const float* p = core2 + jc * 64 + (g << 5) + (g16 << 3);
            float4 v0 = *(const float4*)(p);
            float4 v1 = *(const float4*)(p + 4);
            float vv[8] = { v0.x, v0.y, v0.z, v0.w, v1.x, v1.y, v1.z, v1.w };
            #pragma unroll
            for (int e = 0; e < 8; e++) {
                unsigned short hb = f2bf_rn(vv[e]);
                bh[i][g][e] = (short)hb;
                bl[i][g][e] = (short)f2bf_rn(vv[e] - bf2f(hb));
            }
        }
    }
    int r4 = g16 << 2;
    for (int m = 0; m < 16; ++m) {
        int arow = (m << 4) + cl;
        int sw = arow & 7;
        int abase = arow * 64;
        short8 ah0 = *(short8*)(whi + abase + (((0 + g16) ^ sw) << 3));
        short8 ah1 = *(short8*)(whi + abase + (((4 + g16) ^ sw) << 3));
        short8 al0 = *(short8*)(wlo + abase + (((0 + g16) ^ sw) << 3));
        short8 al1 = *(short8*)(wlo + abase + (((4 + g16) ^ sw) << 3));
        #pragma unroll
        for (int i = 0; i < 4; i++) {
            f32x4 c = { 0.f, 0.f, 0.f, 0.f };
            c = __builtin_amdgcn_mfma_f32_16x16x32_bf16(ah0, bh[i][0], c, 0, 0, 0);
            c = __builtin_amdgcn_mfma_f32_16x16x32_bf16(ah1, bh[i][1], c, 0, 0, 0);
            c = __builtin_amdgcn_mfma_f32_16x16x32_bf16(al0, bh[i][0], c, 0, 0, 0);
            c = __builtin_amdgcn_mfma_f32_16x16x32_bf16(al1, bh[i][1], c, 0, 0, 0);
            c = __builtin_amdgcn_mfma_f32_16x16x32_bf16(ah0, bl[i][0], c, 0, 0, 0);
            c = __builtin_amdgcn_mfma_f32_16x16x32_bf16(ah1, bl[i][1], c, 0, 0, 0);
            int n = wave + (i << 2);
            if (n < 13) {
                int i2 = (n << 4) + cl;
                if (i2 < NV2) {
                    int i1b = (m << 4) + r4;
                    #pragma unroll
                    for (int rg = 0; rg < 4; rg++) {
                        int i1 = i1b + rg;
                        if (i1 < 250) out[obase + i1 * NV2 + i2] = c[rg];
                    }
                }
            }
        }
    }
}

extern "C" void kernel_launch(void* const* d_in, const int* in_sizes, int n_in,
                              void* d_out, int out_size, void* d_ws, size_t ws_size,
                              hipStream_t stream)
{
    const int*   ids    = (const int*)d_in[0];
    const float* core1  = (const float*)d_in[1];   // [250,32,2]
    const float* core2  = (const float*)d_in[2];   // [200,2,32]
    const float* norm_w = (const float*)d_in[3];   // [4,1024]
    const float* adec   = (const float*)d_in[4];   // [4,4]
    const float* Bm     = (const float*)d_in[5];   // [4,1024,4]
    const float* Cm     = (const float*)d_in[6];   // [4,4,1024]
    const float* W1     = (const float*)d_in[7];   // [4,1024,8]
    const float* W2     = (const float*)d_in[8];   // [4,8,1024]
    const float* fw     = (const float*)d_in[9];   // [1024]
    float* out = (float*)d_out;

    float* X  = (float*)d_ws;                      // [2048,1024]
    float* U0 = X + NROWS * DD;                    // [2048,4]
    float* U1 = U0 + NROWS * 4;                    // [2048,4]

    k_embed_bproj<<<NROWS, 256, 0, stream>>>(ids, core1, core2, norm_w, Bm, X, U0);
    float* Uc = U0; float* Un = U1;
    for (int l = 0; l < 4; l++) {
        int has_next = (l < 3) ? 1 : 0;
        const float* nwn = has_next ? (norm_w + (l + 1) * DD) : norm_w;
        const float* bmn = has_next ? (Bm + (l + 1) * DD * 4) : Bm;
        k_layer<<<NROWS, 256, 0, stream>>>(X, Uc, adec + l * 4, Cm + l * 4 * DD,
                                           norm_w + l * DD, W1 + l * DD * 8, W2 + l * 8 * DD,
                                           nwn, bmn, Un, has_next);
        float* tmp = Uc; Uc = Un; Un = tmp;
    }
    k_logits<<<NROWS, 256, 0, stream>>>(X, fw, core1, core2, out);
}